// Round 15
// baseline (110.197 us; speedup 1.0000x reference)
//
#include <hip/hip_runtime.h>

// LSTM_13451837571407 — R15: R9 EXACT + merged-reciprocal activation.
// R12-R14 postmortem: prefetch, MFMA-hoist, launch-bounds all neutral-to-
// negative around R9 (103.9µs) -> schedule is locally optimal; kernel is
// trans-issue + chain-latency bound. Last op-count lever: rcp pairs merged
// via 1/a,1/b = (b,a)*rcp(a*b): 4 rcp -> 2 rcp per act2 (-8cy issue, -2
// trans slots each), products bounded << fp32 overflow for this data.
//
// Datapath (verified; absmax pinned at 2.441e-4 output-quant floor R2-R14):
//   layer 0: gates = x@W_ih0^T + (b_ih0+b_hh0)        (h=c=0, K padded 14->16)
//   layer l>=1: gates = h@(W_ih[l-1]+W_hh[l])^T + bc  (input==hidden quirk)
//   rows i,f,o scaled by -log2e (sigmoid=1/(1+exp2(y)));
//   rows g scaled by 2log2e (tanh=(exp2(y)-1)/(exp2(y)+1)).
//   W = fp16_hi + fp16_lo (22 bits), h = fp16 (cvt_pkrtz); one
//   v_mfma_f32_16x16x32_f16 with A=[Wh|Wl], B=[hf|hf] per gate-quadrant
//   (K32 = two stacked K16 frags, proven R7). Lane's D rows == its next-layer
//   B k-slots (zero cross-lane traffic).

typedef _Float16 f16x8 __attribute__((ext_vector_type(8)));
typedef _Float16 f16x2 __attribute__((ext_vector_type(2)));
typedef float f32x4 __attribute__((ext_vector_type(4)));
typedef float f32x2 __attribute__((ext_vector_type(2)));

#if __has_builtin(__builtin_amdgcn_mfma_f32_16x16x32_f16)
__device__ __forceinline__ f32x4 mfma32h(f16x8 a, f16x8 b, f32x4 c) {
    return __builtin_amdgcn_mfma_f32_16x16x32_f16(a, b, c, 0, 0, 0);
}
#else
__device__ __forceinline__ f32x4 mfma32h(f16x8 a, f16x8 b, f32x4 c) {
    asm volatile("v_mfma_f32_16x16x32_f16 %0, %1, %2, %0\n\ts_nop 7\n\ts_nop 7"
                 : "+v"(c) : "v"(a), "v"(b));
    return c;
}
#endif

#define NLOG2E  (-1.4426950408889634f)
#define G2LOG2E (2.8853900817779268f)
#define THREADS 1024
#define WAVES_PB (THREADS / 64)
#define NBLOCKS 512
#define NTILES 2

// LSTM nonlinearity on a pair of units (packed f32x2); rows pre-scaled.
// Merged reciprocals: one v_rcp_f32 serves both lanes of each division pair.
__device__ __forceinline__ void act2(f32x2 yi, f32x2 yf, f32x2 yg, f32x2 yo,
                                     f32x2& c, f32x2& h) {
    f32x2 Ei, Ef, Eg, Eo;
    Ei[0] = __builtin_amdgcn_exp2f(yi[0]); Ei[1] = __builtin_amdgcn_exp2f(yi[1]);
    Ef[0] = __builtin_amdgcn_exp2f(yf[0]); Ef[1] = __builtin_amdgcn_exp2f(yf[1]);
    Eg[0] = __builtin_amdgcn_exp2f(yg[0]); Eg[1] = __builtin_amdgcn_exp2f(yg[1]);
    Eo[0] = __builtin_amdgcn_exp2f(yo[0]); Eo[1] = __builtin_amdgcn_exp2f(yo[1]);
    const f32x2 one = {1.f, 1.f};
    const f32x2 Di = Ei + one, Df = Ef + one, Do = Eo + one;
    const f32x2 P = __builtin_elementwise_fma(Di, Eg, Di);           // Di*(Eg+1)
    const f32x2 num = __builtin_elementwise_fma(
        Eg, Df, __builtin_elementwise_fma(c, P, -Df));               // (Eg-1)Df+cP
    const f32x2 DfP = Df * P;
    // c = num/DfP per lane via single rcp of the product
    const float R1 = __builtin_amdgcn_rcpf(DfP[0] * DfP[1]);
    const f32x2 DfPs = {DfP[1], DfP[0]};                             // swapped
    c = (num * DfPs) * (f32x2){R1, R1};
    const f32x2 cg = c * (f32x2){G2LOG2E, G2LOG2E};
    f32x2 Ec;
    Ec[0] = __builtin_amdgcn_exp2f(cg[0]); Ec[1] = __builtin_amdgcn_exp2f(cg[1]);
    const f32x2 Q = __builtin_elementwise_fma(Do, Ec, Do);           // Do*(Ec+1)
    const float R2 = __builtin_amdgcn_rcpf(Q[0] * Q[1]);
    const f32x2 Qs = {Q[1], Q[0]};                                   // swapped
    const f32x2 hnum = __builtin_elementwise_fma(Ec, Qs, -Qs);       // (Ec-1)*Qs
    h = hnum * (f32x2){R2, R2};
}

#define LOP(v) __builtin_shufflevector(v, v, 0, 1)
#define HIP2(v) __builtin_shufflevector(v, v, 2, 3)

// duplicate-quad fp16 B fragment via packed RTZ converts: [h0..h3 | h0..h3]
__device__ __forceinline__ f16x8 make_bfrag(f32x2 ha, f32x2 hb) {
    const f16x2 p0 = __builtin_bit_cast(f16x2, __builtin_amdgcn_cvt_pkrtz(ha[0], ha[1]));
    const f16x2 p1 = __builtin_bit_cast(f16x2, __builtin_amdgcn_cvt_pkrtz(hb[0], hb[1]));
    return (f16x8){p0[0], p0[1], p1[0], p1[1], p0[0], p0[1], p1[0], p1[1]};
}

__global__ __launch_bounds__(THREADS, 2) void lstm_mfma_kernel(
    const float* __restrict__ x,      // [B][14]
    const float* __restrict__ W_ih0,  // [64][14]
    const float* __restrict__ W_ih,   // [7][64][16]
    const float* __restrict__ W_hh,   // [8][64][16]
    const float* __restrict__ b_ih,   // [8][64]
    const float* __restrict__ b_hh,   // [8][64]
    const float* __restrict__ fc_w,   // [16]
    const float* __restrict__ fc_b,   // [1]
    float* __restrict__ out,          // [B]
    int nB)
{
    // fragment-major: sWF[(l*4+t)*64 + lane] = 8 halfs [Wh0..3 | Wl0..3]
    __shared__ __align__(16) short sWF[8 * 4 * 64 * 8];  // 32 KB
    __shared__ __align__(16) float sB[8 * 64];
    __shared__ __align__(16) float sFC[20];

    const int tid = threadIdx.x;

    for (int slot = tid; slot < 2048; slot += THREADS) {
        const int l = slot >> 8;
        const int t = (slot >> 6) & 3;
        const int ln = slot & 63;
        const int row = t * 16 + (ln & 15);
        const int k0 = (ln >> 4) * 4;
        const float scale = (t == 2) ? G2LOG2E : NLOG2E;
        short frag[8];
        #pragma unroll
        for (int j = 0; j < 4; ++j) {
            const int k = k0 + j;
            float w;
            if (l == 0) w = (k < 14) ? W_ih0[row * 14 + k] : 0.0f;
            else        w = W_ih[(l - 1) * 1024 + row * 16 + k]
                          + W_hh[l * 1024 + row * 16 + k];
            w *= scale;
            const _Float16 wh = (_Float16)w;            // RNE fp16 hi
            const float wres = w - (float)wh;
            const _Float16 wl = (_Float16)wres;         // fp16 lo (22 bits total)
            frag[j]     = __builtin_bit_cast(short, wh);
            frag[4 + j] = __builtin_bit_cast(short, wl);
        }
        *(short4*)(sWF + slot * 8)     = make_short4(frag[0], frag[1], frag[2], frag[3]);
        *(short4*)(sWF + slot * 8 + 4) = make_short4(frag[4], frag[5], frag[6], frag[7]);
    }
    for (int idx = tid; idx < 512; idx += THREADS) {
        const int row = idx & 63;
        const float scale = ((row >> 4) == 2) ? G2LOG2E : NLOG2E;
        sB[idx] = (b_ih[idx] + b_hh[idx]) * scale;
    }
    if (tid < 16) sFC[tid] = fc_w[tid];
    if (tid == 16) sFC[16] = fc_b[0];
    __syncthreads();

    const int lane = tid & 63;
    const int wv = tid >> 6;
    const int bcol = lane & 15;   // batch within tile
    const int hi = lane >> 4;     // k-quad / D-row group

    const int n_grp = (nB + (16 * NTILES - 1)) / (16 * NTILES);
    const int waves_total = NBLOCKS * WAVES_PB;
    const int iters = (n_grp + waves_total - 1) / waves_total;
    const int gw = blockIdx.x * WAVES_PB + wv;

    const short* wbase = sWF + (lane << 3);
    const float* bbase = sB + hi * 4;

    const f32x4 fw4 = *(const f32x4*)(sFC + hi * 4);
    const f32x2 fwa = LOP(fw4), fwb = HIP2(fw4);
    const float fb = sFC[16];

    for (int it = 0; it < iters; ++it) {
        const int grp = gw * iters + it;
        if (grp >= n_grp) break;

        int bidx[NTILES];
        f32x2 ha[NTILES], hb[NTILES];
        f16x8 Bf[NTILES];
        f32x2 ca[NTILES], cb[NTILES];

        #pragma unroll
        for (int m = 0; m < NTILES; ++m) {
            const int b = grp * (16 * NTILES) + m * 16 + bcol;
            bidx[m] = b;
            const int bc = b < nB ? b : nB - 1;
            const float* xr = x + bc * 14 + hi * 4;
            const float2 p = *(const float2*)xr;
            ha[m][0] = p.x; ha[m][1] = p.y;
            if (hi < 3) {
                const float2 q = *(const float2*)(xr + 2);
                hb[m][0] = q.x; hb[m][1] = q.y;
            } else { hb[m] = (f32x2){0.f, 0.f}; }
            Bf[m] = make_bfrag(ha[m], hb[m]);
            ca[m] = (f32x2){0.f, 0.f};
            cb[m] = (f32x2){0.f, 0.f};
        }

        #pragma unroll
        for (int l = 0; l < 8; ++l) {
            // shared per-layer loads: 4 weight frags [Wh|Wl] + 4 bias quads
            f16x8 fr[4];
            f32x4 bias[4];
            #pragma unroll
            for (int t = 0; t < 4; ++t) {
                fr[t] = *(const f16x8*)(wbase + ((l * 4 + t) << 9));
                bias[t] = *(const f32x4*)(bbase + l * 64 + t * 16);
            }
            #pragma unroll
            for (int m = 0; m < NTILES; ++m) {
                f32x4 a[4];
                #pragma unroll
                for (int t = 0; t < 4; ++t) {
                    // (Wh+Wl)·hf in one K32 MFMA (two stacked K16 fragments)
                    a[t] = mfma32h(fr[t], Bf[m], bias[t]);
                }
                act2(LOP(a[0]), LOP(a[1]), LOP(a[2]), LOP(a[3]), ca[m], ha[m]);
                act2(HIP2(a[0]), HIP2(a[1]), HIP2(a[2]), HIP2(a[3]), cb[m], hb[m]);
                Bf[m] = make_bfrag(ha[m], hb[m]);
            }
        }

        // ---- FC head: dot(h, fc_w), reduce across 4 hi-lane groups ----
        #pragma unroll
        for (int m = 0; m < NTILES; ++m) {
            f32x2 s = ha[m] * fwa;
            s = __builtin_elementwise_fma(hb[m], fwb, s);
            float p = s[0] + s[1];
            p += __shfl_xor(p, 16, 64);
            p += __shfl_xor(p, 32, 64);
            if (hi == 0 && bidx[m] < nB) out[bidx[m]] = p + fb;
        }
    }
}

extern "C" void kernel_launch(void* const* d_in, const int* in_sizes, int n_in,
                              void* d_out, int out_size, void* d_ws, size_t ws_size,
                              hipStream_t stream) {
    const float* x     = (const float*)d_in[0];
    const float* W_ih0 = (const float*)d_in[1];
    const float* W_ih  = (const float*)d_in[2];
    const float* W_hh  = (const float*)d_in[3];
    const float* b_ih  = (const float*)d_in[4];
    const float* b_hh  = (const float*)d_in[5];
    const float* fc_w  = (const float*)d_in[6];
    const float* fc_b  = (const float*)d_in[7];
    float* out = (float*)d_out;

    const int B = in_sizes[0] / 14;
    lstm_mfma_kernel<<<NBLOCKS, THREADS, 0, stream>>>(
        x, W_ih0, W_ih, W_hh, b_ih, b_hh, fc_w, fc_b, out, B);
}

// Round 16
// 104.085 us; speedup vs baseline: 1.0587x; 1.0587x over previous
//
#include <hip/hip_runtime.h>

// LSTM_13451837571407 — R16: R9 EXACT + cvt_pkrtz make_bfrag (single variable).
// R15 postmortem: merged-rcp regressed (chain got longer); R12-R15 show the
// binder is chain latency/pipe phasing at max TLP. Last untested isolated
// lever: pkrtz h->fp16 B-frag (2 instr + bit_cast assembly vs 4 cvt + packs),
// which both cuts ~4% issue and shortens the h->Bf critical path. Numerically
// proven (absmax bit-identical in R11/R14/R15).
//
// Datapath (verified; absmax pinned at 2.441e-4 output-quant floor R2-R15):
//   layer 0: gates = x@W_ih0^T + (b_ih0+b_hh0)        (h=c=0, K padded 14->16)
//   layer l>=1: gates = h@(W_ih[l-1]+W_hh[l])^T + bc  (input==hidden quirk)
//   rows i,f,o scaled by -log2e (sigmoid=1/(1+exp2(y)));
//   rows g scaled by 2log2e (tanh=(exp2(y)-1)/(exp2(y)+1)).
//   W = fp16_hi + fp16_lo (22 bits), h = fp16; one v_mfma_f32_16x16x32_f16
//   with A=[Wh|Wl], B=[hf|hf] per gate-quadrant (K32 = two stacked K16 frags,
//   proven R7). Lane's D rows == its next-layer B k-slots (zero shuffles).

typedef _Float16 f16x8 __attribute__((ext_vector_type(8)));
typedef float f32x4 __attribute__((ext_vector_type(4)));
typedef float f32x2 __attribute__((ext_vector_type(2)));

#if __has_builtin(__builtin_amdgcn_mfma_f32_16x16x32_f16)
__device__ __forceinline__ f32x4 mfma32h(f16x8 a, f16x8 b, f32x4 c) {
    return __builtin_amdgcn_mfma_f32_16x16x32_f16(a, b, c, 0, 0, 0);
}
#else
__device__ __forceinline__ f32x4 mfma32h(f16x8 a, f16x8 b, f32x4 c) {
    asm volatile("v_mfma_f32_16x16x32_f16 %0, %1, %2, %0\n\ts_nop 7\n\ts_nop 7"
                 : "+v"(c) : "v"(a), "v"(b));
    return c;
}
#endif

#define NLOG2E  (-1.4426950408889634f)
#define G2LOG2E (2.8853900817779268f)
#define THREADS 1024
#define WAVES_PB (THREADS / 64)
#define NBLOCKS 512
#define NTILES 2

// LSTM nonlinearity on a pair of units (packed f32x2); rows pre-scaled.
__device__ __forceinline__ void act2(f32x2 yi, f32x2 yf, f32x2 yg, f32x2 yo,
                                     f32x2& c, f32x2& h) {
    f32x2 Ei, Ef, Eg, Eo;
    Ei[0] = __builtin_amdgcn_exp2f(yi[0]); Ei[1] = __builtin_amdgcn_exp2f(yi[1]);
    Ef[0] = __builtin_amdgcn_exp2f(yf[0]); Ef[1] = __builtin_amdgcn_exp2f(yf[1]);
    Eg[0] = __builtin_amdgcn_exp2f(yg[0]); Eg[1] = __builtin_amdgcn_exp2f(yg[1]);
    Eo[0] = __builtin_amdgcn_exp2f(yo[0]); Eo[1] = __builtin_amdgcn_exp2f(yo[1]);
    const f32x2 one = {1.f, 1.f};
    const f32x2 Di = Ei + one, Df = Ef + one, Do = Eo + one;
    const f32x2 P = __builtin_elementwise_fma(Di, Eg, Di);           // Di*(Eg+1)
    const f32x2 num = __builtin_elementwise_fma(
        Eg, Df, __builtin_elementwise_fma(c, P, -Df));               // (Eg-1)Df+cP
    const f32x2 DfP = Df * P;
    f32x2 R1;
    R1[0] = __builtin_amdgcn_rcpf(DfP[0]); R1[1] = __builtin_amdgcn_rcpf(DfP[1]);
    c = num * R1;
    const f32x2 cg = c * (f32x2){G2LOG2E, G2LOG2E};
    f32x2 Ec;
    Ec[0] = __builtin_amdgcn_exp2f(cg[0]); Ec[1] = __builtin_amdgcn_exp2f(cg[1]);
    const f32x2 Q = __builtin_elementwise_fma(Do, Ec, Do);           // Do*(Ec+1)
    f32x2 R2;
    R2[0] = __builtin_amdgcn_rcpf(Q[0]); R2[1] = __builtin_amdgcn_rcpf(Q[1]);
    h = __builtin_elementwise_fma(Ec, R2, -R2);                      // (Ec-1)/Q
}

#define LOP(v) __builtin_shufflevector(v, v, 0, 1)
#define HIP2(v) __builtin_shufflevector(v, v, 2, 3)

// duplicate-quad fp16 B fragment: 2x v_cvt_pkrtz + pure register aliasing
__device__ __forceinline__ f16x8 make_bfrag(f32x2 ha, f32x2 hb) {
    const unsigned w0 = __builtin_bit_cast(unsigned,
        __builtin_amdgcn_cvt_pkrtz(ha[0], ha[1]));
    const unsigned w1 = __builtin_bit_cast(unsigned,
        __builtin_amdgcn_cvt_pkrtz(hb[0], hb[1]));
    const uint4 u = {w0, w1, w0, w1};
    return __builtin_bit_cast(f16x8, u);
}

__global__ __launch_bounds__(THREADS, 2) void lstm_mfma_kernel(
    const float* __restrict__ x,      // [B][14]
    const float* __restrict__ W_ih0,  // [64][14]
    const float* __restrict__ W_ih,   // [7][64][16]
    const float* __restrict__ W_hh,   // [8][64][16]
    const float* __restrict__ b_ih,   // [8][64]
    const float* __restrict__ b_hh,   // [8][64]
    const float* __restrict__ fc_w,   // [16]
    const float* __restrict__ fc_b,   // [1]
    float* __restrict__ out,          // [B]
    int nB)
{
    // fragment-major: sWF[(l*4+t)*64 + lane] = 8 halfs [Wh0..3 | Wl0..3]
    __shared__ __align__(16) short sWF[8 * 4 * 64 * 8];  // 32 KB
    __shared__ __align__(16) float sB[8 * 64];
    __shared__ __align__(16) float sFC[20];

    const int tid = threadIdx.x;

    for (int slot = tid; slot < 2048; slot += THREADS) {
        const int l = slot >> 8;
        const int t = (slot >> 6) & 3;
        const int ln = slot & 63;
        const int row = t * 16 + (ln & 15);
        const int k0 = (ln >> 4) * 4;
        const float scale = (t == 2) ? G2LOG2E : NLOG2E;
        short frag[8];
        #pragma unroll
        for (int j = 0; j < 4; ++j) {
            const int k = k0 + j;
            float w;
            if (l == 0) w = (k < 14) ? W_ih0[row * 14 + k] : 0.0f;
            else        w = W_ih[(l - 1) * 1024 + row * 16 + k]
                          + W_hh[l * 1024 + row * 16 + k];
            w *= scale;
            const _Float16 wh = (_Float16)w;            // RNE fp16 hi
            const float wres = w - (float)wh;
            const _Float16 wl = (_Float16)wres;         // fp16 lo (22 bits total)
            frag[j]     = __builtin_bit_cast(short, wh);
            frag[4 + j] = __builtin_bit_cast(short, wl);
        }
        *(short4*)(sWF + slot * 8)     = make_short4(frag[0], frag[1], frag[2], frag[3]);
        *(short4*)(sWF + slot * 8 + 4) = make_short4(frag[4], frag[5], frag[6], frag[7]);
    }
    for (int idx = tid; idx < 512; idx += THREADS) {
        const int row = idx & 63;
        const float scale = ((row >> 4) == 2) ? G2LOG2E : NLOG2E;
        sB[idx] = (b_ih[idx] + b_hh[idx]) * scale;
    }
    if (tid < 16) sFC[tid] = fc_w[tid];
    if (tid == 16) sFC[16] = fc_b[0];
    __syncthreads();

    const int lane = tid & 63;
    const int wv = tid >> 6;
    const int bcol = lane & 15;   // batch within tile
    const int hi = lane >> 4;     // k-quad / D-row group

    const int n_grp = (nB + (16 * NTILES - 1)) / (16 * NTILES);
    const int waves_total = NBLOCKS * WAVES_PB;
    const int iters = (n_grp + waves_total - 1) / waves_total;
    const int gw = blockIdx.x * WAVES_PB + wv;

    const short* wbase = sWF + (lane << 3);
    const float* bbase = sB + hi * 4;

    const f32x4 fw4 = *(const f32x4*)(sFC + hi * 4);
    const f32x2 fwa = LOP(fw4), fwb = HIP2(fw4);
    const float fb = sFC[16];

    for (int it = 0; it < iters; ++it) {
        const int grp = gw * iters + it;
        if (grp >= n_grp) break;

        int bidx[NTILES];
        f32x2 ha[NTILES], hb[NTILES];
        f16x8 Bf[NTILES];
        f32x2 ca[NTILES], cb[NTILES];

        #pragma unroll
        for (int m = 0; m < NTILES; ++m) {
            const int b = grp * (16 * NTILES) + m * 16 + bcol;
            bidx[m] = b;
            const int bc = b < nB ? b : nB - 1;
            const float* xr = x + bc * 14 + hi * 4;
            const float2 p = *(const float2*)xr;
            ha[m][0] = p.x; ha[m][1] = p.y;
            if (hi < 3) {
                const float2 q = *(const float2*)(xr + 2);
                hb[m][0] = q.x; hb[m][1] = q.y;
            } else { hb[m] = (f32x2){0.f, 0.f}; }
            Bf[m] = make_bfrag(ha[m], hb[m]);
            ca[m] = (f32x2){0.f, 0.f};
            cb[m] = (f32x2){0.f, 0.f};
        }

        #pragma unroll
        for (int l = 0; l < 8; ++l) {
            // shared per-layer loads: 4 weight frags [Wh|Wl] + 4 bias quads
            f16x8 fr[4];
            f32x4 bias[4];
            #pragma unroll
            for (int t = 0; t < 4; ++t) {
                fr[t] = *(const f16x8*)(wbase + ((l * 4 + t) << 9));
                bias[t] = *(const f32x4*)(bbase + l * 64 + t * 16);
            }
            #pragma unroll
            for (int m = 0; m < NTILES; ++m) {
                f32x4 a[4];
                #pragma unroll
                for (int t = 0; t < 4; ++t) {
                    // (Wh+Wl)·hf in one K32 MFMA (two stacked K16 fragments)
                    a[t] = mfma32h(fr[t], Bf[m], bias[t]);
                }
                act2(LOP(a[0]), LOP(a[1]), LOP(a[2]), LOP(a[3]), ca[m], ha[m]);
                act2(HIP2(a[0]), HIP2(a[1]), HIP2(a[2]), HIP2(a[3]), cb[m], hb[m]);
                Bf[m] = make_bfrag(ha[m], hb[m]);
            }
        }

        // ---- FC head: dot(h, fc_w), reduce across 4 hi-lane groups ----
        #pragma unroll
        for (int m = 0; m < NTILES; ++m) {
            f32x2 s = ha[m] * fwa;
            s = __builtin_elementwise_fma(hb[m], fwb, s);
            float p = s[0] + s[1];
            p += __shfl_xor(p, 16, 64);
            p += __shfl_xor(p, 32, 64);
            if (hi == 0 && bidx[m] < nB) out[bidx[m]] = p + fb;
        }
    }
}

extern "C" void kernel_launch(void* const* d_in, const int* in_sizes, int n_in,
                              void* d_out, int out_size, void* d_ws, size_t ws_size,
                              hipStream_t stream) {
    const float* x     = (const float*)d_in[0];
    const float* W_ih0 = (const float*)d_in[1];
    const float* W_ih  = (const float*)d_in[2];
    const float* W_hh  = (const float*)d_in[3];
    const float* b_ih  = (const float*)d_in[4];
    const float* b_hh  = (const float*)d_in[5];
    const float* fc_w  = (const float*)d_in[6];
    const float* fc_b  = (const float*)d_in[7];
    float* out = (float*)d_out;

    const int B = in_sizes[0] / 14;
    lstm_mfma_kernel<<<NBLOCKS, THREADS, 0, stream>>>(
        x, W_ih0, W_ih, W_hh, b_ih, b_hh, fc_w, fc_b, out, B);
}